// Round 13
// baseline (84.647 us; speedup 1.0000x reference)
//
#include <hip/hip_runtime.h>

#define BB 8
#define CC 512
#define SS 1024   // H*W
#define EMB 512
#define HEADS 8
#define DH 64
#define GROUPS 32
#define CPG 16
#define EPS 1e-5f

typedef __bf16 bf16x8 __attribute__((ext_vector_type(8)));
typedef __bf16 bf16x4 __attribute__((ext_vector_type(4)));
typedef float f32x4 __attribute__((ext_vector_type(4)));
typedef unsigned short u16x4 __attribute__((ext_vector_type(4)));

__device__ inline unsigned short f2bf(float f) {
    union { float f; unsigned u; } c; c.f = f;
    unsigned u = c.u + 0x7FFF + ((c.u >> 16) & 1);   // RNE
    return (unsigned short)(u >> 16);
}

#if defined(__has_builtin)
#if __has_builtin(__builtin_amdgcn_exp2f)
#define EXP2F(x) __builtin_amdgcn_exp2f(x)
#endif
#endif
#ifndef EXP2F
#define EXP2F(x) __expf(0.69314718f * (x))
#endif

#define MFMA16(a, b, c) __builtin_amdgcn_mfma_f32_16x16x32_bf16((a), (b), (c), 0, 0, 0)
#define GLOAD_LDS16(g, s)                                                     \
    __builtin_amdgcn_global_load_lds(                                         \
        (const __attribute__((address_space(1))) void*)(g),                   \
        (__attribute__((address_space(3))) void*)(s), 16, 0, 0)

// ---------------------------------------------------------------------------
// Prep (fused): blocks 0..4095 transpose x -> xT bf16; 4096..5119 transpose
// the four weight matrices -> Wt bf16 (K-major).
// ---------------------------------------------------------------------------
__global__ __launch_bounds__(256) void prep_all(
    const float* __restrict__ x,
    const float* __restrict__ Wq, const float* __restrict__ Wk,
    const float* __restrict__ Wv, const float* __restrict__ Wo,
    unsigned short* __restrict__ xT, unsigned short* __restrict__ Wt)
{
    __shared__ float tile[32][33];
    const int t = threadIdx.x;

    if (blockIdx.x < 4096) {
        const int i  = blockIdx.x;
        const int s0 = (i & 31) * 32;
        const int c0 = ((i >> 5) & 15) * 32;
        const int b  = i >> 9;
        {
            int c = t >> 3, s4 = (t & 7) * 4;
            float4 v = *(const float4*)(x + ((size_t)b * CC + c0 + c) * SS + s0 + s4);
            tile[c][s4] = v.x; tile[c][s4 + 1] = v.y;
            tile[c][s4 + 2] = v.z; tile[c][s4 + 3] = v.w;
        }
        __syncthreads();
        {
            int sr = t >> 3, c4 = (t & 7) * 4;
            u16x4 o;
            #pragma unroll
            for (int i2 = 0; i2 < 4; ++i2) o[i2] = f2bf(tile[c4 + i2][sr]);
            *(u16x4*)(xT + ((size_t)(b << 10) + s0 + sr) * CC + c0 + c4) = o;
        }
    } else {
        const int i  = blockIdx.x - 4096;
        const int k0 = (i & 15) * 32;
        const int n0 = ((i >> 4) & 15) * 32;
        const int z  = i >> 8;
        const float* W = (z == 0) ? Wq : (z == 1) ? Wk : (z == 2) ? Wv : Wo;
        unsigned short* dst = Wt + (size_t)z * EMB * CC;
        {
            int k = t >> 3, n4 = (t & 7) * 4;
            float4 v = *(const float4*)(W + (size_t)(k0 + k) * EMB + n0 + n4);
            tile[k][n4] = v.x; tile[k][n4 + 1] = v.y;
            tile[k][n4 + 2] = v.z; tile[k][n4 + 3] = v.w;
        }
        __syncthreads();
        {
            int n = t >> 3, k4 = (t & 7) * 4;
            u16x4 o;
            #pragma unroll
            for (int i2 = 0; i2 < 4; ++i2) o[i2] = f2bf(tile[k4 + i2][n]);
            *(u16x4*)(dst + (size_t)(n0 + n) * CC + k0 + k4) = o;
        }
    }
}

// ---------------------------------------------------------------------------
// MFMA GEMM core pieces.  GEMM_IDX defines thread indices; GEMM_LOOP runs
// the 128x128/BK=32 double-buffered loop.  SWP=1 swaps MFMA operands so the
// output is C^T: lane&15 indexes m (row), regs index n (4 consecutive cols)
// -> vectorized [S][DH] stores in the Q/K epilogue.
// ---------------------------------------------------------------------------
#define GEMM_IDX                                                               \
    const int t = threadIdx.x, w = t >> 6, l = t & 63;                         \
    const int wr = w >> 1, wc = w & 1;                                         \
    const int rl = l & 15, kh = l >> 4;

#define GEMM_LOOP(Aptr, Bptr, SWP)                                             \
    {                                                                          \
        const int srow = w * 32 + (l >> 2);                                    \
        const int sslot = (l & 3) ^ ((srow >> 1) & 3);                         \
        const char* Ag0 = (const char*)(Aptr) + (size_t)(m0 + srow) * 1024 + sslot * 16;      \
        const char* Ag1 = (const char*)(Aptr) + (size_t)(m0 + srow + 16) * 1024 + (((l & 3) ^ (((srow + 16) >> 1) & 3)) * 16); \
        const char* Bg0 = (const char*)(Bptr) + (size_t)(n0 + srow) * 1024 + sslot * 16;      \
        const char* Bg1 = (const char*)(Bptr) + (size_t)(n0 + srow + 16) * 1024 + (((l & 3) ^ (((srow + 16) >> 1) & 3)) * 16); \
        for (int kt = 0; kt < 16; ++kt) {                                      \
            if (kt == 0) {                                                     \
                GLOAD_LDS16(Ag0, lds + w * 2048);                              \
                GLOAD_LDS16(Ag1, lds + w * 2048 + 1024);                       \
                GLOAD_LDS16(Bg0, lds + 8192 + w * 2048);                       \
                GLOAD_LDS16(Bg1, lds + 8192 + w * 2048 + 1024);                \
                __syncthreads();                                               \
            }                                                                  \
            const int buf = kt & 1;                                            \
            if (kt < 15) {                                                     \
                const int kb = (kt + 1) * 64;                                  \
                char* Al = lds + (buf ^ 1) * 16384;                            \
                char* Bl = Al + 8192;                                          \
                GLOAD_LDS16(Ag0 + kb, Al + w * 2048);                          \
                GLOAD_LDS16(Ag1 + kb, Al + w * 2048 + 1024);                   \
                GLOAD_LDS16(Bg0 + kb, Bl + w * 2048);                          \
                GLOAD_LDS16(Bg1 + kb, Bl + w * 2048 + 1024);                   \
            }                                                                  \
            const char* Al = lds + buf * 16384;                                \
            const char* Bl = Al + 8192;                                        \
            bf16x8 af[4], bfr[4];                                              \
            _Pragma("unroll")                                                  \
            for (int i = 0; i < 4; ++i) {                                      \
                int row = wr * 64 + i * 16 + rl;                               \
                af[i] = *(const bf16x8*)(Al + row * 64 + ((kh ^ ((row >> 1) & 3)) << 4)); \
                int col = wc * 64 + i * 16 + rl;                               \
                bfr[i] = *(const bf16x8*)(Bl + col * 64 + ((kh ^ ((col >> 1) & 3)) << 4)); \
            }                                                                  \
            _Pragma("unroll")                                                  \
            for (int i = 0; i < 4; ++i)                                        \
                _Pragma("unroll")                                              \
                for (int j = 0; j < 4; ++j)                                    \
                    acc[i][j] = (SWP) ? MFMA16(bfr[j], af[i], acc[i][j])       \
                                      : MFMA16(af[i], bfr[j], acc[i][j]);      \
            __syncthreads();                                                   \
        }                                                                      \
    }

// QKV: A = xT, B = Wt[z].  Q scaled by DH^-0.5*log2(e).  Q/K bf16
// [B][H][S][DH] written via SWAPPED core (vector bf16x4 stores, 4 consecutive
// d);  V bf16 transposed [B][H][DH][S] via normal core (4 consecutive s).
__global__ __launch_bounds__(256) void qkv_mm(
    const unsigned short* __restrict__ xT, const unsigned short* __restrict__ Wt,
    const float* __restrict__ bq, const float* __restrict__ bk,
    const float* __restrict__ bv,
    unsigned short* __restrict__ Qb, unsigned short* __restrict__ Kb,
    unsigned short* __restrict__ Vb)
{
    __shared__ __align__(16) char lds[32768];
    const int z = blockIdx.z;
    const unsigned short* Bt = Wt + (size_t)z * EMB * CC;
    const float* bias = (z == 0) ? bq : (z == 1) ? bk : bv;
    const int m0 = blockIdx.x * 128, n0 = blockIdx.y * 128;
    GEMM_IDX
    f32x4 acc[4][4] = {};

    if (z == 2) {
        GEMM_LOOP(xT, Bt, 0)
        // V^T: [B][H][DH][S], 4 consecutive s -> vector store
        #pragma unroll
        for (int i = 0; i < 4; ++i) {
            #pragma unroll
            for (int j = 0; j < 4; ++j) {
                int n = n0 + wc * 64 + j * 16 + rl;
                int h = n >> 6, d = n & 63;
                float bi = bias[n];
                int mb = m0 + wr * 64 + i * 16 + kh * 4;
                int b = mb >> 10, s = mb & 1023;
                bf16x4 o;
                #pragma unroll
                for (int r = 0; r < 4; ++r) o[r] = (__bf16)(acc[i][j][r] + bi);
                *(bf16x4*)((__bf16*)Vb + (((size_t)(b * HEADS + h)) * DH + d) * SS + s) = o;
            }
        }
    } else {
        GEMM_LOOP(xT, Bt, 1)
        unsigned short* outp = (z == 0) ? Qb : Kb;
        const float qs = (z == 0) ? 0.1803368801f : 1.0f;   // 0.125*log2(e)
        // C^T layout: m = m0+wr*64+i*16+rl (fixed/thread), n = ...+kh*4+r
        #pragma unroll
        for (int i = 0; i < 4; ++i) {
            int m = m0 + wr * 64 + i * 16 + rl;
            int b = m >> 10, s = m & 1023;
            #pragma unroll
            for (int j = 0; j < 4; ++j) {
                int nb = n0 + wc * 64 + j * 16 + kh * 4;
                int h = nb >> 6, d0 = nb & 63;
                float4 bi4 = *(const float4*)(bias + nb);
                bf16x4 o;
                o[0] = (__bf16)((acc[i][j][0] + bi4.x) * qs);
                o[1] = (__bf16)((acc[i][j][1] + bi4.y) * qs);
                o[2] = (__bf16)((acc[i][j][2] + bi4.z) * qs);
                o[3] = (__bf16)((acc[i][j][3] + bi4.w) * qs);
                *(bf16x4*)((__bf16*)outp +
                           (((size_t)(b * HEADS + h)) * SS + s) * DH + d0) = o;
            }
        }
    }
}

// proj: A = AO bf16, B = Wot; out Y bf16 [B][C][S] = acc + bo + residual.
__global__ __launch_bounds__(256) void proj_mm(
    const unsigned short* __restrict__ AO, const unsigned short* __restrict__ Wot,
    const float* __restrict__ bo, const float* __restrict__ x,
    unsigned short* __restrict__ Yb)
{
    __shared__ __align__(16) char lds[32768];
    const int m0 = blockIdx.x * 128, n0 = blockIdx.y * 128;
    GEMM_IDX
    f32x4 acc[4][4] = {};

    GEMM_LOOP(AO, Wot, 0)

    #pragma unroll
    for (int i = 0; i < 4; ++i) {
        #pragma unroll
        for (int j = 0; j < 4; ++j) {
            int n = n0 + wc * 64 + j * 16 + rl;
            float bi = bo[n];
            int mb = m0 + wr * 64 + i * 16 + kh * 4;
            int b = mb >> 10, s = mb & 1023;
            const float4 xr = *(const float4*)(x + ((size_t)b * CC + n) * SS + s);
            bf16x4 o;
            o[0] = (__bf16)(acc[i][j][0] + bi + xr.x);
            o[1] = (__bf16)(acc[i][j][1] + bi + xr.y);
            o[2] = (__bf16)(acc[i][j][2] + bi + xr.z);
            o[3] = (__bf16)(acc[i][j][3] + bi + xr.w);
            *(bf16x4*)((__bf16*)Yb + ((size_t)b * CC + n) * SS + s) = o;
        }
    }
}

// ---------------------------------------------------------------------------
// MFMA flash attention — EXACT R6 v3.1 structure (best measured, race-free):
// KVBLK=64, 4 waves x 32 q-rows, grid 512, 48KB LDS.  K + V^T staged via
// global_load_lds dbuf (pre-swizzled source), stage issued at TOP of tile,
// single trailing __syncthreads per tile (drains stage loads AFTER the
// ~1500cy compute phase covers L2 latency; also fences the dbuf WAR).
// Defer-max softmax in exp2 domain (scale folded into Q), LDS P round-trip,
// setprio on MFMA clusters, XCD-aware remap.
// ---------------------------------------------------------------------------
__global__ __launch_bounds__(256) void attn_mfma(
    const unsigned short* __restrict__ Q, const unsigned short* __restrict__ K,
    const unsigned short* __restrict__ V, unsigned short* __restrict__ Aout)
{
    __shared__ __align__(16) char lds[49152];

    // XCD-aware remap: 8 q-blocks of one (b,h) stay on one XCD.
    const int wg  = blockIdx.x;          // 0..511
    const int xcd = wg & 7;
    const int idx = wg >> 3;             // 0..63
    const int pair = xcd * 8 + (idx >> 3);   // 0..63
    const int qb   = idx & 7;
    const int h = pair & 7;
    const int b = pair >> 3;
    const int q0 = qb * 128;

    const size_t kbase = ((size_t)b * HEADS + h) * SS * DH;   // Q,K layout
    const size_t vbase = ((size_t)b * HEADS + h) * DH * SS;   // V^T layout

    const int t  = threadIdx.x;
    const int w  = t >> 6;
    const int l  = t & 63;
    const int g  = l >> 4;
    const int qi = l & 15;
    char* Pl = lds + 32768 + w * 4096;

    // Q fragments resident in registers: 2 q-columns (u) x 2 k-halves
    bf16x8 qf[2][2];
    #pragma unroll
    for (int u = 0; u < 2; ++u) {
        const unsigned short* qrow =
            Q + kbase + (size_t)(q0 + w * 32 + u * 16 + qi) * DH;
        qf[u][0] = *(const bf16x8*)(qrow + g * 8);
        qf[u][1] = *(const bf16x8*)(qrow + 32 + g * 8);
    }

    // staging addresses (pre-swizzled source, linear LDS dest)
    const int srow = t >> 3;             // 0..31
    const int seg  = t & 7;
    const unsigned short* kg0 = K + kbase + (size_t)srow * DH + ((seg ^ (srow & 7)) * 8);
    const unsigned short* vg0 = V + vbase + (size_t)srow * SS + ((seg ^ (srow & 7)) * 8);

#define ATTN_STAGE(bb, ktn)                                                    \
    GLOAD_LDS16(kg0 + (ktn) * 4096, lds + (bb) + t * 16);                      \
    GLOAD_LDS16(kg0 + (ktn) * 4096 + 2048, lds + (bb) + 4096 + t * 16);        \
    GLOAD_LDS16(vg0 + (ktn) * 64, lds + (bb) + 8192 + t * 16);                 \
    GLOAD_LDS16(vg0 + (ktn) * 64 + 32768, lds + (bb) + 12288 + t * 16);

    f32x4 O[4][2] = {};
    float m2[2]   = {-1e30f, -1e30f};
    float lsum[2] = {0.f, 0.f};

    int bufb = 0;
    ATTN_STAGE(0, 0)
    __syncthreads();

    for (int kt = 0; kt < 16; ++kt) {
        if (kt < 15) { ATTN_STAGE(bufb ^ 16384, kt + 1) }

        const char* Kl = lds + bufb;
        const char* Vl = lds + bufb + 8192;

        // ---- QK^T swapped (scores already in log2 domain via Q scale) ----
        f32x4 st[4][2] = {};
        __builtin_amdgcn_s_setprio(1);
        #pragma unroll
        for (int tt = 0; tt < 4; ++tt) {
            int row = tt * 16 + qi;
            bf16x8 kf0 = *(const bf16x8*)(Kl + row * 128 +
                          ((g * 16) ^ ((row & 7) << 4)));
            bf16x8 kf1 = *(const bf16x8*)(Kl + row * 128 +
                          ((64 + g * 16) ^ ((row & 7) << 4)));
            #pragma unroll
            for (int u = 0; u < 2; ++u) {
                st[tt][u] = MFMA16(kf0, qf[u][0], st[tt][u]);
                st[tt][u] = MFMA16(kf1, qf[u][1], st[tt][u]);
            }
        }
        __builtin_amdgcn_s_setprio(0);

        // ---- softmax (exp2 domain, defer-max THR=8), per q-column ----
        float pmax[2] = {-1e30f, -1e30f};
        #pragma unroll
        for (int tt = 0; tt < 4; ++tt)
            #pragma unroll
            for (int u = 0; u < 2; ++u)
                #pragma unroll
                for (int r = 0; r < 4; ++r)
                    pmax[u] = fmaxf(pmax[u], st[tt][u][r]);
        #pragma unroll
        for (int u = 0; u < 2; ++u) {
            if (!__all(pmax[u] <= m2[u] + 8.0f)) {
                float gm = fmaxf(pmax[u], __shfl_xor(pmax[u], 16));
                gm = fmaxf(gm, __shfl_xor(gm, 32));
                float newm = fmaxf(m2[u], gm);
                float alpha = EXP2F(m2[u] - newm);
                #pragma unroll
                for (int dt = 0; dt < 4; ++dt)
                    #pragma unroll
                    for (int r = 0; r < 4; ++r) O[dt][u][r] *= alpha;
                lsum[u] *= alpha;
                m2[u] = newm;
            }
            #pragma unroll
            for (int tt = 0; tt < 4; ++tt) {
                bf16x4 pk;
                #pragma unroll
                for (int r = 0; r < 4; ++r) {
                    float p = EXP2F(st[tt][u][r] - m2[u]);
                    lsum[u] += p;
                    pk[r] = (__bf16)p;
                }
                *(bf16x4*)(Pl + u * 2048 + qi * 128 +
                           ((tt * 32 + g * 8) ^ ((qi & 7) << 4))) = pk;
            }
        }

        // ---- PV: O^T[d][q] += V^T[d][k] P^T[k][q] ----
        bf16x8 pf[2][2];
        #pragma unroll
        for (int u = 0; u < 2; ++u)
            #pragma unroll
            for (int hh = 0; hh < 2; ++hh)
                pf[u][hh] = *(const bf16x8*)(Pl + u * 2048 + qi * 128 +
                             ((hh * 64 + g * 16) ^ ((qi & 7) << 4)));
        __builtin_amdgcn_s_setprio(1);
        #pragma unroll
        for (int dt = 0; dt < 4; ++dt) {
            int d = dt * 16 + qi;
            bf16x8 vf0 = *(const bf16x8*)(Vl + d * 128 + ((g * 16) ^ ((d & 7) << 4)));
            bf16x8 vf1 = *(const bf16x8*)(Vl + d * 128 + ((64 + g * 16) ^ ((d & 7) << 4)));
            #pragma unroll
            for (int u = 0; u < 2; ++u) {
                O[dt][u] = MFMA16(vf0, pf[u][0], O[dt][u]);
                O[dt][u] = MFMA16(vf1, pf[u][1], O[dt][u]);
            }
        }
        __builtin_amdgcn_s_setprio(0);

        __syncthreads();
        bufb ^= 16384;
    }

    // ---- epilogue ----
    #pragma unroll
    for (int u = 0; u < 2; ++u) {
        float ls = lsum[u];
        ls += __shfl_xor(ls, 16);
        ls += __shfl_xor(ls, 32);
        const float inv = __builtin_amdgcn_rcpf(ls);
        unsigned short* orow = Aout +
            ((size_t)b * SS + q0 + w * 32 + u * 16 + qi) * EMB + h * DH;
        #pragma unroll
        for (int dt = 0; dt < 4; ++dt) {
            bf16x4 o;
            #pragma unroll
            for (int r = 0; r < 4; ++r) o[r] = (__bf16)(O[dt][u][r] * inv);
            *(bf16x4*)((__bf16*)orow + dt * 16 + g * 4) = o;
        }
    }
#undef ATTN_STAGE
}

// ---------------------------------------------------------------------------
// GroupNorm: Y bf16 [B][C][S] read ONCE into LDS (32KB/group), stats from
// LDS, normalize from LDS, fp32 out.  One block per (group, batch).
// ---------------------------------------------------------------------------
__global__ __launch_bounds__(256) void gnorm3(
    const __bf16* __restrict__ Yb, const float* __restrict__ gw,
    const float* __restrict__ gb, float* __restrict__ out)
{
    __shared__ __align__(16) __bf16 ybuf[CPG * SS];   // 32 KB
    __shared__ float red[8];
    __shared__ float stats[2];

    const int grp = blockIdx.x;
    const int b   = blockIdx.y;
    const int t   = threadIdx.x;
    const size_t base = ((size_t)b * CC + grp * CPG) * SS;   // 16384 elems
    const __bf16* src = Yb + base;

    float sum = 0.f, sq = 0.f;
    #pragma unroll
    for (int i = 0; i < 8; ++i) {
        int off = i * 2048 + t * 8;
        bf16x8 v = *(const bf16x8*)(src + off);
        *(bf16x8*)(ybuf + off) = v;
        #pragma unroll
        for (int j = 0; j < 8; ++j) {
            float f = (float)v[j];
            sum += f; sq += f * f;
        }
    }
    #pragma unroll
    for (int off = 32; off; off >>= 1) {
        sum += __shfl_down(sum, off);
        sq  += __shfl_down(sq, off);
    }
    const int wid = t >> 6;
    if ((t & 63) == 0) { red[wid] = sum; red[4 + wid] = sq; }
    __syncthreads();
    if (t == 0) {
        float s1 = red[0] + red[1] + red[2] + red[3];
        float s2 = red[4] + red[5] + red[6] + red[7];
        float mean = s1 / (float)(CPG * SS);
        float var  = s2 / (float)(CPG * SS) - mean * mean;
        stats[0] = mean;
        stats[1] = rsqrtf(var + EPS);
    }
    __syncthreads();
    const float mean = stats[0], rs = stats[1];

    #pragma unroll
    for (int i = 0; i < 8; ++i) {
        int off = i * 2048 + t * 8;
        int ch = grp * CPG + (off >> 10);
        float wgt = gw[ch] * rs, bet = gb[ch] - mean * rs * gw[ch];
        bf16x8 v = *(const bf16x8*)(ybuf + off);
        float4 o0, o1;
        o0.x = (float)v[0] * wgt + bet; o0.y = (float)v[1] * wgt + bet;
        o0.z = (float)v[2] * wgt + bet; o0.w = (float)v[3] * wgt + bet;
        o1.x = (float)v[4] * wgt + bet; o1.y = (float)v[5] * wgt + bet;
        o1.z = (float)v[6] * wgt + bet; o1.w = (float)v[7] * wgt + bet;
        *(float4*)(out + base + off)     = o0;
        *(float4*)(out + base + off + 4) = o1;
    }
}

// ---------------------------------------------------------------------------
extern "C" void kernel_launch(void* const* d_in, const int* in_sizes, int n_in,
                              void* d_out, int out_size, void* d_ws, size_t ws_size,
                              hipStream_t stream) {
    const float* x   = (const float*)d_in[0];
    const float* Wq  = (const float*)d_in[1];
    const float* bq  = (const float*)d_in[2];
    const float* Wk  = (const float*)d_in[3];
    const float* bk  = (const float*)d_in[4];
    const float* Wv  = (const float*)d_in[5];
    const float* bv  = (const float*)d_in[6];
    const float* Wo  = (const float*)d_in[7];
    const float* bo  = (const float*)d_in[8];
    const float* gnw = (const float*)d_in[9];
    const float* gnb = (const float*)d_in[10];
    float* out = (float*)d_out;
    char* ws  = (char*)d_ws;

    unsigned short* xT  = (unsigned short*)(ws);                       //  8 MB
    unsigned short* Wt  = (unsigned short*)(ws + 8388608);             //  2 MB
    unsigned short* Qb  = (unsigned short*)(ws + 10485760);            //  8 MB
    unsigned short* Kb  = (unsigned short*)(ws + 18874368);            //  8 MB
    unsigned short* Vb  = (unsigned short*)(ws + 27262976);            //  8 MB (V^T)
    unsigned short* AO  = (unsigned short*)(ws + 35651584);            //  8 MB
    unsigned short* Yb  = (unsigned short*)(ws + 44040192);            //  8 MB (bf16)

    prep_all<<<dim3(5120), 256, 0, stream>>>(x, Wq, Wk, Wv, Wo, xT, Wt);
    qkv_mm<<<dim3(64, 4, 3), 256, 0, stream>>>(xT, Wt, bq, bk, bv, Qb, Kb, Vb);
    attn_mfma<<<dim3(512), 256, 0, stream>>>(Qb, Kb, Vb, AO);
    proj_mm<<<dim3(64, 4), 256, 0, stream>>>(AO, Wt + (size_t)3 * EMB * CC, bo, x, Yb);
    gnorm3<<<dim3(32, 8), 256, 0, stream>>>((const __bf16*)Yb, gnw, gnb, out);
}